// Round 1
// baseline (359.994 us; speedup 1.0000x reference)
//
#include <hip/hip_runtime.h>
#include <stdint.h>

#define F_DIM 768
#define E_DIM 512

typedef __attribute__((ext_vector_type(4))) float f32x4;
typedef __attribute__((ext_vector_type(8))) __bf16 bf16x8;

__device__ __forceinline__ uint16_t f2bf(float f) {
  uint32_t u = __builtin_bit_cast(uint32_t, f);
  return (uint16_t)((u + 0x7FFFu + ((u >> 16) & 1u)) >> 16);
}

#define GLOAD_LDS16(g, l) __builtin_amdgcn_global_load_lds(                 \
    (const __attribute__((address_space(1))) void*)(g),                     \
    (__attribute__((address_space(3))) void*)(l), 16, 0, 0)

// ---------------------------------------------------------------------------
// Embed GEMM: C[row][e] = sum_f src[row][f] * gw[e][f] + gb[e], bf16 out.
// 128x128 tile, BK=64, 4 waves (2x2), 16x16x32 bf16 MFMA.
// fp32 inputs converted to bf16 during reg-staged LDS writes.
// LDS layout XOR-swizzled: byte(row,k) = row*128 + ((k/8 ^ (row&7))<<4) + (k&7)*2
// ---------------------------------------------------------------------------
__global__ __launch_bounds__(256) void embed_gemm(
    const float* __restrict__ src, const float* __restrict__ gw,
    const float* __restrict__ gb, uint16_t* __restrict__ out) {
  __shared__ uint4 smem4[2048];  // A: bytes [0,16384), B: [16384,32768)
  char* smc = (char*)smem4;
  const int t = threadIdx.x;
  const int l = t & 63, w = t >> 6, wm = w >> 1, wn = w & 1;
  const int bx = blockIdx.x, by = blockIdx.y;
  const int g = l >> 4, x7 = l & 7;

  f32x4 acc[4][4];
#pragma unroll
  for (int a_ = 0; a_ < 4; ++a_)
#pragma unroll
    for (int b_ = 0; b_ < 4; ++b_) acc[a_][b_] = (f32x4){0.f, 0.f, 0.f, 0.f};

  const int rr0 = t >> 3;   // row-within-chunk (c adds 32)
  const int ss  = t & 7;    // logical 8-elem slot

  for (int kk = 0; kk < F_DIM; kk += 64) {
    __syncthreads();
#pragma unroll
    for (int c = 0; c < 4; ++c) {
      const int rr = c * 32 + rr0;
      const int wb = rr * 128 + ((ss ^ (rr & 7)) << 4);
      {
        const float* p = src + (size_t)(bx * 128 + rr) * F_DIM + kk + ss * 8;
        float4 lo = *(const float4*)p;
        float4 hi = *(const float4*)(p + 4);
        uint4 pk;
        pk.x = f2bf(lo.x) | ((uint32_t)f2bf(lo.y) << 16);
        pk.y = f2bf(lo.z) | ((uint32_t)f2bf(lo.w) << 16);
        pk.z = f2bf(hi.x) | ((uint32_t)f2bf(hi.y) << 16);
        pk.w = f2bf(hi.z) | ((uint32_t)f2bf(hi.w) << 16);
        *(uint4*)(smc + wb) = pk;
      }
      {
        const float* p = gw + (size_t)(by * 128 + rr) * F_DIM + kk + ss * 8;
        float4 lo = *(const float4*)p;
        float4 hi = *(const float4*)(p + 4);
        uint4 pk;
        pk.x = f2bf(lo.x) | ((uint32_t)f2bf(lo.y) << 16);
        pk.y = f2bf(lo.z) | ((uint32_t)f2bf(lo.w) << 16);
        pk.z = f2bf(hi.x) | ((uint32_t)f2bf(hi.y) << 16);
        pk.w = f2bf(hi.z) | ((uint32_t)f2bf(hi.w) << 16);
        *(uint4*)(smc + 16384 + wb) = pk;
      }
    }
    __syncthreads();
#pragma unroll
    for (int ks = 0; ks < 2; ++ks) {
      const int slotoff = ((ks * 4 + g) ^ x7) << 4;
      bf16x8 af[4], bfr[4];
#pragma unroll
      for (int fm = 0; fm < 4; ++fm)
        af[fm] = *(const bf16x8*)(smc + (wm * 64 + fm * 16 + (l & 15)) * 128 + slotoff);
#pragma unroll
      for (int fn = 0; fn < 4; ++fn)
        bfr[fn] = *(const bf16x8*)(smc + 16384 + (wn * 64 + fn * 16 + (l & 15)) * 128 + slotoff);
#pragma unroll
      for (int fm = 0; fm < 4; ++fm)
#pragma unroll
        for (int fn = 0; fn < 4; ++fn)
          acc[fm][fn] = __builtin_amdgcn_mfma_f32_16x16x32_bf16(
              af[fm], bfr[fn], acc[fm][fn], 0, 0, 0);
    }
  }

  // Epilogue: bias + bf16 store. C layout: col=lane&15, row=(lane>>4)*4+reg.
  const int colb = by * 128 + wn * 64;
#pragma unroll
  for (int fn = 0; fn < 4; ++fn) {
    const int col = colb + fn * 16 + (l & 15);
    const float bias = gb[col];
#pragma unroll
    for (int fm = 0; fm < 4; ++fm) {
      const int rowb = bx * 128 + wm * 64 + fm * 16 + g * 4;
#pragma unroll
      for (int v = 0; v < 4; ++v)
        out[(size_t)(rowb + v) * E_DIM + col] = f2bf(acc[fm][fn][v] + bias);
    }
  }
}

// ---------------------------------------------------------------------------
// In-place L2 row normalization of bf16 [rows][512]; one wave per row.
// ---------------------------------------------------------------------------
__global__ __launch_bounds__(256) void l2norm_rows(uint16_t* __restrict__ eg) {
  const int row = blockIdx.x * 4 + (threadIdx.x >> 6);
  const int l = threadIdx.x & 63;
  uint16_t* p = eg + (size_t)row * E_DIM + l * 8;
  uint4 v = *(const uint4*)p;
  uint32_t wd[4] = {v.x, v.y, v.z, v.w};
  float f[8];
#pragma unroll
  for (int i = 0; i < 4; ++i) {
    f[2 * i]     = __builtin_bit_cast(float, (wd[i] & 0xFFFFu) << 16);
    f[2 * i + 1] = __builtin_bit_cast(float, wd[i] & 0xFFFF0000u);
  }
  float s = 0.f;
#pragma unroll
  for (int i = 0; i < 8; ++i) s += f[i] * f[i];
#pragma unroll
  for (int m = 1; m < 64; m <<= 1) s += __shfl_xor(s, m);
  const float inv = 1.0f / fmaxf(sqrtf(s), 1e-12f);
  uint4 o;
  o.x = f2bf(f[0] * inv) | ((uint32_t)f2bf(f[1] * inv) << 16);
  o.y = f2bf(f[2] * inv) | ((uint32_t)f2bf(f[3] * inv) << 16);
  o.z = f2bf(f[4] * inv) | ((uint32_t)f2bf(f[5] * inv) << 16);
  o.w = f2bf(f[6] * inv) | ((uint32_t)f2bf(f[7] * inv) << 16);
  *(uint4*)p = o;
}

// ---------------------------------------------------------------------------
// Main fused kernel: A = Xn @ Dn^T (cosine sims), a^3 * (2r-1), reduce over
// the 128-col tile, atomicAdd per-row partials into echo[N].
// 128x128 tile, BK=64, global_load_lds (linear dest) + pre-swizzled source.
// ---------------------------------------------------------------------------
__global__ __launch_bounds__(256) void minerva_main(
    const uint16_t* __restrict__ Xn, const uint16_t* __restrict__ Dn,
    const float* __restrict__ rin, float* __restrict__ echo) {
  __shared__ uint4 smem4[2048];
  char* smc = (char*)smem4;
  const int t = threadIdx.x;
  const int l = t & 63, w = t >> 6, wm = w >> 1, wn = w & 1;
  const int bx = blockIdx.x, by = blockIdx.y;
  const int g = l >> 4, x7 = l & 7;

  f32x4 acc[4][4];
#pragma unroll
  for (int a_ = 0; a_ < 4; ++a_)
#pragma unroll
    for (int b_ = 0; b_ < 4; ++b_) acc[a_][b_] = (f32x4){0.f, 0.f, 0.f, 0.f};

  // Staging: linear LDS dest (thread t -> byte t*16 within 4KB chunk i),
  // global source pre-swizzled so LDS(row,slot_l) holds k-slot slot_l^(row&7).
  const int rr0 = t >> 3, ss = t & 7;
  const int s0 = ss ^ (rr0 & 7);
  const uint16_t* pA = Xn + (size_t)(bx * 128 + rr0) * E_DIM + s0 * 8;
  const uint16_t* pB = Dn + (size_t)(by * 128 + rr0) * E_DIM + s0 * 8;
  char* ldsA = smc + t * 16;
  char* ldsB = smc + 16384 + t * 16;

  for (int kk = 0; kk < E_DIM; kk += 64) {
    __syncthreads();
#pragma unroll
    for (int i = 0; i < 4; ++i) {
      GLOAD_LDS16(pA + (size_t)i * 32 * E_DIM + kk, ldsA + i * 4096);
      GLOAD_LDS16(pB + (size_t)i * 32 * E_DIM + kk, ldsB + i * 4096);
    }
    __syncthreads();
#pragma unroll
    for (int ks = 0; ks < 2; ++ks) {
      const int slotoff = ((ks * 4 + g) ^ x7) << 4;
      bf16x8 af[4], bfr[4];
#pragma unroll
      for (int fm = 0; fm < 4; ++fm)
        af[fm] = *(const bf16x8*)(smc + (wm * 64 + fm * 16 + (l & 15)) * 128 + slotoff);
#pragma unroll
      for (int fn = 0; fn < 4; ++fn)
        bfr[fn] = *(const bf16x8*)(smc + 16384 + (wn * 64 + fn * 16 + (l & 15)) * 128 + slotoff);
#pragma unroll
      for (int fm = 0; fm < 4; ++fm)
#pragma unroll
        for (int fn = 0; fn < 4; ++fn)
          acc[fm][fn] = __builtin_amdgcn_mfma_f32_16x16x32_bf16(
              af[fm], bfr[fn], acc[fm][fn], 0, 0, 0);
    }
  }

  // Epilogue: cube, weight by r2, reduce across the wave's 64-col stripe.
  const int jb = by * 128 + wn * 64;
  float r2[4];
#pragma unroll
  for (int fn = 0; fn < 4; ++fn)
    r2[fn] = rin[jb + fn * 16 + (l & 15)] * 2.0f - 1.0f;
  const int rowb = bx * 128 + wm * 64;
#pragma unroll
  for (int fm = 0; fm < 4; ++fm) {
#pragma unroll
    for (int v = 0; v < 4; ++v) {
      float sum = 0.f;
#pragma unroll
      for (int fn = 0; fn < 4; ++fn) {
        const float a = acc[fm][fn][v];
        sum += a * a * a * r2[fn];
      }
      // reduce across the 16 lanes sharing this row (cols)
      sum += __shfl_xor(sum, 1);
      sum += __shfl_xor(sum, 2);
      sum += __shfl_xor(sum, 4);
      sum += __shfl_xor(sum, 8);
      if ((l & 15) == 0)
        atomicAdd(&echo[rowb + fm * 16 + g * 4 + v], sum);
    }
  }
}

// ---------------------------------------------------------------------------
__global__ __launch_bounds__(256) void head_sigmoid(
    const float* __restrict__ echo, const float* __restrict__ hw,
    const float* __restrict__ hb, float* __restrict__ out, int n) {
  const int i = blockIdx.x * 256 + threadIdx.x;
  if (i < n) {
    const float e = echo[i] * hw[0] + hb[0];
    out[i] = 1.0f / (1.0f + __expf(-e));
  }
}

// ---------------------------------------------------------------------------
extern "C" void kernel_launch(void* const* d_in, const int* in_sizes, int n_in,
                              void* d_out, int out_size, void* d_ws, size_t ws_size,
                              hipStream_t stream) {
  const float* X  = (const float*)d_in[0];
  const float* D  = (const float*)d_in[1];
  const float* r  = (const float*)d_in[2];
  const float* gw = (const float*)d_in[3];
  const float* gb = (const float*)d_in[4];
  const float* hw = (const float*)d_in[5];
  const float* hb = (const float*)d_in[6];
  float* out = (float*)d_out;
  const int N = in_sizes[0] / F_DIM;  // 8192
  const int M = in_sizes[1] / F_DIM;  // 16384

  uint16_t* Xn = (uint16_t*)d_ws;
  uint16_t* Dn = Xn + (size_t)N * E_DIM;
  float* echo = (float*)((char*)d_ws + (size_t)(N + M) * E_DIM * 2);

  hipMemsetAsync(echo, 0, (size_t)N * sizeof(float), stream);

  dim3 blk(256);
  embed_gemm<<<dim3(N / 128, E_DIM / 128), blk, 0, stream>>>(X, gw, gb, Xn);
  embed_gemm<<<dim3(M / 128, E_DIM / 128), blk, 0, stream>>>(D, gw, gb, Dn);
  l2norm_rows<<<(N + M) / 4, blk, 0, stream>>>(Xn);  // X rows then D rows, contiguous
  minerva_main<<<dim3(N / 128, M / 128), blk, 0, stream>>>(Xn, Dn, r, echo);
  head_sigmoid<<<(N + 255) / 256, blk, 0, stream>>>(echo, hw, hb, out, N);
}

// Round 2
// 330.536 us; speedup vs baseline: 1.0891x; 1.0891x over previous
//
#include <hip/hip_runtime.h>
#include <stdint.h>

#define F_DIM 768
#define E_DIM 512

typedef __attribute__((ext_vector_type(4))) float f32x4;
typedef __attribute__((ext_vector_type(8))) __bf16 bf16x8;

__device__ __forceinline__ uint16_t f2bf(float f) {
  uint32_t u = __builtin_bit_cast(uint32_t, f);
  return (uint16_t)((u + 0x7FFFu + ((u >> 16) & 1u)) >> 16);
}

#define GLOAD_LDS16(g, l) __builtin_amdgcn_global_load_lds(                 \
    (const __attribute__((address_space(1))) void*)(g),                     \
    (__attribute__((address_space(3))) void*)(l), 16, 0, 0)

// ---------------------------------------------------------------------------
// Embed GEMM: C[row][e] = sum_f src[row][f] * gw[e][f] + gb[e], bf16 out.
// 128x128 tile, BK=64, 4 waves (2x2), 16x16x32 bf16 MFMA. (unchanged r1)
// ---------------------------------------------------------------------------
__global__ __launch_bounds__(256) void embed_gemm(
    const float* __restrict__ src, const float* __restrict__ gw,
    const float* __restrict__ gb, uint16_t* __restrict__ out) {
  __shared__ uint4 smem4[2048];  // A: bytes [0,16384), B: [16384,32768)
  char* smc = (char*)smem4;
  const int t = threadIdx.x;
  const int l = t & 63, w = t >> 6, wm = w >> 1, wn = w & 1;
  const int bx = blockIdx.x, by = blockIdx.y;
  const int g = l >> 4, x7 = l & 7;

  f32x4 acc[4][4];
#pragma unroll
  for (int a_ = 0; a_ < 4; ++a_)
#pragma unroll
    for (int b_ = 0; b_ < 4; ++b_) acc[a_][b_] = (f32x4){0.f, 0.f, 0.f, 0.f};

  const int rr0 = t >> 3;
  const int ss  = t & 7;

  for (int kk = 0; kk < F_DIM; kk += 64) {
    __syncthreads();
#pragma unroll
    for (int c = 0; c < 4; ++c) {
      const int rr = c * 32 + rr0;
      const int wb = rr * 128 + ((ss ^ (rr & 7)) << 4);
      {
        const float* p = src + (size_t)(bx * 128 + rr) * F_DIM + kk + ss * 8;
        float4 lo = *(const float4*)p;
        float4 hi = *(const float4*)(p + 4);
        uint4 pk;
        pk.x = f2bf(lo.x) | ((uint32_t)f2bf(lo.y) << 16);
        pk.y = f2bf(lo.z) | ((uint32_t)f2bf(lo.w) << 16);
        pk.z = f2bf(hi.x) | ((uint32_t)f2bf(hi.y) << 16);
        pk.w = f2bf(hi.z) | ((uint32_t)f2bf(hi.w) << 16);
        *(uint4*)(smc + wb) = pk;
      }
      {
        const float* p = gw + (size_t)(by * 128 + rr) * F_DIM + kk + ss * 8;
        float4 lo = *(const float4*)p;
        float4 hi = *(const float4*)(p + 4);
        uint4 pk;
        pk.x = f2bf(lo.x) | ((uint32_t)f2bf(lo.y) << 16);
        pk.y = f2bf(lo.z) | ((uint32_t)f2bf(lo.w) << 16);
        pk.z = f2bf(hi.x) | ((uint32_t)f2bf(hi.y) << 16);
        pk.w = f2bf(hi.z) | ((uint32_t)f2bf(hi.w) << 16);
        *(uint4*)(smc + 16384 + wb) = pk;
      }
    }
    __syncthreads();
#pragma unroll
    for (int ks = 0; ks < 2; ++ks) {
      const int slotoff = ((ks * 4 + g) ^ x7) << 4;
      bf16x8 af[4], bfr[4];
#pragma unroll
      for (int fm = 0; fm < 4; ++fm)
        af[fm] = *(const bf16x8*)(smc + (wm * 64 + fm * 16 + (l & 15)) * 128 + slotoff);
#pragma unroll
      for (int fn = 0; fn < 4; ++fn)
        bfr[fn] = *(const bf16x8*)(smc + 16384 + (wn * 64 + fn * 16 + (l & 15)) * 128 + slotoff);
#pragma unroll
      for (int fm = 0; fm < 4; ++fm)
#pragma unroll
        for (int fn = 0; fn < 4; ++fn)
          acc[fm][fn] = __builtin_amdgcn_mfma_f32_16x16x32_bf16(
              af[fm], bfr[fn], acc[fm][fn], 0, 0, 0);
    }
  }

  const int colb = by * 128 + wn * 64;
#pragma unroll
  for (int fn = 0; fn < 4; ++fn) {
    const int col = colb + fn * 16 + (l & 15);
    const float bias = gb[col];
#pragma unroll
    for (int fm = 0; fm < 4; ++fm) {
      const int rowb = bx * 128 + wm * 64 + fm * 16 + g * 4;
#pragma unroll
      for (int v = 0; v < 4; ++v)
        out[(size_t)(rowb + v) * E_DIM + col] = f2bf(acc[fm][fn][v] + bias);
    }
  }
}

// ---------------------------------------------------------------------------
// In-place L2 row normalization of bf16 [rows][512]; one wave per row.
// ---------------------------------------------------------------------------
__global__ __launch_bounds__(256) void l2norm_rows(uint16_t* __restrict__ eg) {
  const int row = blockIdx.x * 4 + (threadIdx.x >> 6);
  const int l = threadIdx.x & 63;
  uint16_t* p = eg + (size_t)row * E_DIM + l * 8;
  uint4 v = *(const uint4*)p;
  uint32_t wd[4] = {v.x, v.y, v.z, v.w};
  float f[8];
#pragma unroll
  for (int i = 0; i < 4; ++i) {
    f[2 * i]     = __builtin_bit_cast(float, (wd[i] & 0xFFFFu) << 16);
    f[2 * i + 1] = __builtin_bit_cast(float, wd[i] & 0xFFFF0000u);
  }
  float s = 0.f;
#pragma unroll
  for (int i = 0; i < 8; ++i) s += f[i] * f[i];
#pragma unroll
  for (int m = 1; m < 64; m <<= 1) s += __shfl_xor(s, m);
  const float inv = 1.0f / fmaxf(sqrtf(s), 1e-12f);
  uint4 o;
  o.x = f2bf(f[0] * inv) | ((uint32_t)f2bf(f[1] * inv) << 16);
  o.y = f2bf(f[2] * inv) | ((uint32_t)f2bf(f[3] * inv) << 16);
  o.z = f2bf(f[4] * inv) | ((uint32_t)f2bf(f[5] * inv) << 16);
  o.w = f2bf(f[6] * inv) | ((uint32_t)f2bf(f[7] * inv) << 16);
  *(uint4*)p = o;
}

// ---------------------------------------------------------------------------
// Main fused kernel, 256x256 tile, 8 waves (2Mx4N), BK=64, double-buffered
// 128 KiB LDS, phase-interleaved schedule (T3+T4 min + T5):
//   per K-tile: 4 phases of {ds_read subtile | 2x global_load_lds prefetch
//   -> s_barrier -> setprio(1) -> 16 MFMA -> setprio(0) -> s_barrier},
//   one vmcnt(0) per K-tile (at phase 4), raw s_barrier (no vmcnt drain).
// Epilogue: a^3 * (2r-1), reduce over 64-col stripe, atomicAdd into echo.
// ---------------------------------------------------------------------------
__global__ __launch_bounds__(512, 2) void minerva_main256(
    const uint16_t* __restrict__ Xn, const uint16_t* __restrict__ Dn,
    const float* __restrict__ rin, float* __restrict__ echo) {
  extern __shared__ __align__(16) char smem[];  // [2][A:32K][B:32K] = 128 KiB
  const int t_ = threadIdx.x;
  const int l = t_ & 63, w = t_ >> 6;
  const int wm = w >> 2, wn = w & 3;  // 2 x 4 waves -> wave tile 128x64
  const int bx = blockIdx.x, by = blockIdx.y;
  const int g = l >> 4, x7 = l & 7, l15 = l & 15;

  f32x4 acc[8][4];
#pragma unroll
  for (int a_ = 0; a_ < 8; ++a_)
#pragma unroll
    for (int b_ = 0; b_ < 4; ++b_) acc[a_][b_] = (f32x4){0.f, 0.f, 0.f, 0.f};

  // Staging: linear LDS dest, pre-swizzled global source.
  // LDS[R][slot] holds global slot (slot ^ (R&7)); chunk i covers rows i*64..
  const int rr = t_ >> 3, ss = t_ & 7;
  const int s0 = ss ^ (rr & 7);
  const uint16_t* gA = Xn + (size_t)(bx * 256 + rr) * E_DIM + s0 * 8;
  const uint16_t* gB = Dn + (size_t)(by * 256 + rr) * E_DIM + s0 * 8;
  char* ldsDst = smem + t_ * 16;

#define STG_A(CUR, KK, I) GLOAD_LDS16(gA + (size_t)(I) * 64 * E_DIM + (KK), \
                                      ldsDst + (CUR) * 32768 + (I) * 8192)
#define STG_B(CUR, KK, I) GLOAD_LDS16(gB + (size_t)(I) * 64 * E_DIM + (KK), \
                                      ldsDst + 65536 + (CUR) * 32768 + (I) * 8192)

#define PHASE(FM0, KS, READ_B, GL, LAST)                                       \
  {                                                                            \
    const int so = (((KS) * 4 + g) ^ x7) << 4;                                 \
    bf16x8 af[4];                                                              \
    _Pragma("unroll") for (int i_ = 0; i_ < 4; ++i_)                           \
        af[i_] = *(const bf16x8*)(bufA +                                       \
                  (wm * 128 + ((FM0) + i_) * 16 + l15) * 128 + so);            \
    if (READ_B) {                                                              \
      _Pragma("unroll") for (int j_ = 0; j_ < 4; ++j_)                         \
          bfr[j_] = *(const bf16x8*)(bufB +                                    \
                    (wn * 64 + j_ * 16 + l15) * 128 + so);                     \
    }                                                                          \
    GL;                                                                        \
    __builtin_amdgcn_s_barrier();                                              \
    __builtin_amdgcn_s_setprio(1);                                             \
    _Pragma("unroll") for (int i_ = 0; i_ < 4; ++i_)                           \
        _Pragma("unroll") for (int j_ = 0; j_ < 4; ++j_)                       \
            acc[(FM0) + i_][j_] = __builtin_amdgcn_mfma_f32_16x16x32_bf16(     \
                af[i_], bfr[j_], acc[(FM0) + i_][j_], 0, 0, 0);                \
    __builtin_amdgcn_s_setprio(0);                                             \
    if (LAST) asm volatile("s_waitcnt vmcnt(0)" ::: "memory");                 \
    __builtin_amdgcn_s_barrier();                                              \
  }

#define TILE(KKN, CUR, PF)                                                     \
  {                                                                            \
    char* bufA = smem + (CUR) * 32768;                                         \
    char* bufB = smem + 65536 + (CUR) * 32768;                                 \
    bf16x8 bfr[4];                                                             \
    PHASE(0, 0, 1, if (PF) { STG_A(1 - (CUR), KKN, 0); STG_A(1 - (CUR), KKN, 1); }, 0) \
    PHASE(4, 0, 0, if (PF) { STG_A(1 - (CUR), KKN, 2); STG_A(1 - (CUR), KKN, 3); }, 0) \
    PHASE(0, 1, 1, if (PF) { STG_B(1 - (CUR), KKN, 0); STG_B(1 - (CUR), KKN, 1); }, 0) \
    PHASE(4, 1, 0, if (PF) { STG_B(1 - (CUR), KKN, 2); STG_B(1 - (CUR), KKN, 3); }, 1) \
  }

  // Prologue: stage K-tile 0 into buffer 0.
  STG_A(0, 0, 0); STG_A(0, 0, 1); STG_A(0, 0, 2); STG_A(0, 0, 3);
  STG_B(0, 0, 0); STG_B(0, 0, 1); STG_B(0, 0, 2); STG_B(0, 0, 3);
  asm volatile("s_waitcnt vmcnt(0)" ::: "memory");
  __builtin_amdgcn_s_barrier();

  // K = 512 -> 8 K-tiles of 64, double-buffered (2 per loop iteration).
  for (int t2 = 0; t2 < 8; t2 += 2) {
    TILE((t2 + 1) * 64, 0, 1);
    const int pf2 = (t2 < 6);
    TILE((t2 + 2) * 64, 1, pf2);
  }

  // Epilogue: cube, weight by r2, reduce across wave's 64-col stripe.
  const int jb = by * 256 + wn * 64;
  float r2[4];
#pragma unroll
  for (int fn = 0; fn < 4; ++fn)
    r2[fn] = rin[jb + fn * 16 + l15] * 2.0f - 1.0f;
  const int rowb = bx * 256 + wm * 128;
#pragma unroll
  for (int fm = 0; fm < 8; ++fm) {
#pragma unroll
    for (int v = 0; v < 4; ++v) {
      float sum = 0.f;
#pragma unroll
      for (int fn = 0; fn < 4; ++fn) {
        const float a = acc[fm][fn][v];
        sum += a * a * a * r2[fn];
      }
      sum += __shfl_xor(sum, 1);
      sum += __shfl_xor(sum, 2);
      sum += __shfl_xor(sum, 4);
      sum += __shfl_xor(sum, 8);
      if (l15 == 0)
        atomicAdd(&echo[rowb + fm * 16 + g * 4 + v], sum);
    }
  }
#undef STG_A
#undef STG_B
#undef PHASE
#undef TILE
}

// ---------------------------------------------------------------------------
__global__ __launch_bounds__(256) void head_sigmoid(
    const float* __restrict__ echo, const float* __restrict__ hw,
    const float* __restrict__ hb, float* __restrict__ out, int n) {
  const int i = blockIdx.x * 256 + threadIdx.x;
  if (i < n) {
    const float e = echo[i] * hw[0] + hb[0];
    out[i] = 1.0f / (1.0f + __expf(-e));
  }
}

// ---------------------------------------------------------------------------
extern "C" void kernel_launch(void* const* d_in, const int* in_sizes, int n_in,
                              void* d_out, int out_size, void* d_ws, size_t ws_size,
                              hipStream_t stream) {
  const float* X  = (const float*)d_in[0];
  const float* D  = (const float*)d_in[1];
  const float* r  = (const float*)d_in[2];
  const float* gw = (const float*)d_in[3];
  const float* gb = (const float*)d_in[4];
  const float* hw = (const float*)d_in[5];
  const float* hb = (const float*)d_in[6];
  float* out = (float*)d_out;
  const int N = in_sizes[0] / F_DIM;  // 8192
  const int M = in_sizes[1] / F_DIM;  // 16384

  uint16_t* Xn = (uint16_t*)d_ws;
  uint16_t* Dn = Xn + (size_t)N * E_DIM;
  float* echo = (float*)((char*)d_ws + (size_t)(N + M) * E_DIM * 2);

  hipMemsetAsync(echo, 0, (size_t)N * sizeof(float), stream);

  (void)hipFuncSetAttribute((const void*)minerva_main256,
                            hipFuncAttributeMaxDynamicSharedMemorySize, 131072);

  dim3 blk(256);
  embed_gemm<<<dim3(N / 128, E_DIM / 128), blk, 0, stream>>>(X, gw, gb, Xn);
  embed_gemm<<<dim3(M / 128, E_DIM / 128), blk, 0, stream>>>(D, gw, gb, Dn);
  l2norm_rows<<<(N + M) / 4, blk, 0, stream>>>(Xn);  // X rows then D rows
  minerva_main256<<<dim3(N / 256, M / 256), dim3(512), 131072, stream>>>(Xn, Dn, r, echo);
  head_sigmoid<<<(N + 255) / 256, blk, 0, stream>>>(echo, hw, hb, out, N);
}